// Round 7
// baseline (247.811 us; speedup 1.0000x reference)
//
#include <hip/hip_runtime.h>

#define DIM   32
#define HID   64
#define TILES 8              // 16-cell tiles per wave

typedef __attribute__((ext_vector_type(8))) short bf16x8;   // 8 bf16 = 4 VGPRs
typedef __attribute__((ext_vector_type(4))) float f32x4;

// hardware packed f32x2 -> bf16x2 (RNE): result dword = (bf16(lo), bf16(hi))
__device__ __forceinline__ unsigned cvt_pk_bf16(float lo, float hi) {
    unsigned r;
    asm("v_cvt_pk_bf16_f32 %0, %1, %2" : "=v"(r) : "v"(lo), "v"(hi));
    return r;
}
// unpack a (lo,hi) bf16 pair back to f32
__device__ __forceinline__ float bfp_lo(unsigned u) { return __uint_as_float(u << 16); }
__device__ __forceinline__ float bfp_hi(unsigned u) { return __uint_as_float(u & 0xFFFF0000u); }

// permlane32 swap via the 2-result intrinsic (distinct result regs guaranteed).
__device__ __forceinline__ void plswap(unsigned &a, unsigned &b) {
    auto r = __builtin_amdgcn_permlane32_swap((int)a, (int)b, false, false);
    a = (unsigned)r[0];
    b = (unsigned)r[1];
}

// permlane16 swap by value: a' = [a@q0, b@q0, a@q2, b@q2], b' = [a@q1, b@q1, a@q3, b@q3]
struct f2 { float a, b; };
__device__ __forceinline__ f2 plswap16v(float a, float b) {
    auto r = __builtin_amdgcn_permlane16_swap(__float_as_int(a), __float_as_int(b),
                                              false, false);
    return { __int_as_float(r[0]), __int_as_float(r[1]) };
}

// sum over the 4 quads (lanes c, c+16, c+32, c+48) -> all lanes get the total. All-VALU.
__device__ __forceinline__ float quad_sum(float x) {
    auto r1 = __builtin_amdgcn_permlane32_swap(__float_as_int(x), __float_as_int(x),
                                               false, false);
    float t = __int_as_float(r1[0]) + __int_as_float(r1[1]);   // x[l] + x[l^32]
    auto r2 = __builtin_amdgcn_permlane16_swap(__float_as_int(t), __float_as_int(t),
                                               false, false);
    return __int_as_float(r2[0]) + __int_as_float(r2[1]);      // + 16-crossing
}

union bfu { bf16x8 v; unsigned u[4]; };

__global__ __launch_bounds__(128, 3) void behavior_mfma(
    const float* __restrict__ g_in,   // [N, 32]
    const float* __restrict__ pot,    // [N]
    const float* __restrict__ W1,     // [33, 64]
    const float* __restrict__ b1,     // [64]
    const float* __restrict__ W2,     // [64, 32]
    const float* __restrict__ b2,     // [32]
    float* __restrict__ out)          // [N, 32]
{
    const int tid  = threadIdx.x;
    const int lane = tid & 63;
    const int quad = lane >> 4;        // 0..3
    const int mrow = lane & 15;        // 0..15
    const int wave = tid >> 6;         // 0..1

    const long cell0 = ((long)blockIdx.x * 2 + wave) * (TILES * 16);

    // ---------- 3-slot tile ring (slot = t % 3); first loads issued BEFORE weight setup
    float4 gA[3], gB[3]; float pV[3];
    auto loadT = [&](int s, long cb) {
        const float* gp = g_in + (cb + mrow) * DIM + quad * 8;
        gA[s] = ((const float4*)gp)[0];
        gB[s] = ((const float4*)gp)[1];
        pV[s] = pot[cb + mrow];                       // pot[cell=mrow]
    };
    loadT(0, cell0);
    loadT(1, cell0 + 16);
    loadT(2, cell0 + 32);

    // ---- W1 chunks as A-fragments of swapped GEMM1 (D = W1^T x^T).
    bf16x8 w1f[4];
    #pragma unroll
    for (int nb = 0; nb < 4; ++nb) {
        bfu t;
        #pragma unroll
        for (int jp = 0; jp < 4; ++jp)
            t.u[jp] = cvt_pk_bf16(W1[(quad * 8 + 2 * jp)     * HID + nb * 16 + mrow],
                                  W1[(quad * 8 + 2 * jp + 1) * HID + nb * 16 + mrow]);
        w1f[nb] = t.v;
    }
    // ---- W2 A-fragments with PERMUTED k-labeling matching pl32-only h redistribution:
    //   hmap(quad,j) = (quad>>1)*16 + (quad&1)*4 + (j>>2)*8 + (j&3)
    bf16x8 w2f[2][2];
    #pragma unroll
    for (int kc = 0; kc < 2; ++kc)
        #pragma unroll
        for (int nc = 0; nc < 2; ++nc) {
            bfu t;
            #pragma unroll
            for (int jp = 0; jp < 4; ++jp) {
                const int j0 = 2 * jp;
                const int r0 = kc * 32 + (quad >> 1) * 16 + (quad & 1) * 4
                             + ((j0 >> 2) << 3) + (j0 & 3);
                t.u[jp] = cvt_pk_bf16(W2[r0 * DIM + nc * 16 + mrow],
                                      W2[(r0 + 1) * DIM + nc * 16 + mrow]);
            }
            w2f[kc][nc] = t.v;
        }
    // ---- identity A-fragment (natural k=dim labeling) for 0.3*g pass-through
    bf16x8 aid[2];
    #pragma unroll
    for (int nc = 0; nc < 2; ++nc) {
        bfu t;
        #pragma unroll
        for (int jp = 0; jp < 4; ++jp) {
            unsigned lo = (quad * 8 + 2 * jp     == nc * 16 + mrow) ? 0x00003F80u : 0u;
            unsigned hi = (quad * 8 + 2 * jp + 1 == nc * 16 + mrow) ? 0x3F800000u : 0u;
            t.u[jp] = lo | hi;
        }
        aid[nc] = t.v;
    }
    // ---- bias path, PACKED bf16 pairs (r pairs (0,1),(2,3)): halves fixed VGPR cost.
    // c1[r] row = hid nb*16+quad*4+r, col = cell mrow.
    unsigned w1pp[4][2], b1p[4][2];
    #pragma unroll
    for (int nb = 0; nb < 4; ++nb)
        #pragma unroll
        for (int p = 0; p < 2; ++p) {
            w1pp[nb][p] = cvt_pk_bf16(W1[32 * HID + nb * 16 + quad * 4 + 2 * p],
                                      W1[32 * HID + nb * 16 + quad * 4 + 2 * p + 1]);
            b1p[nb][p]  = cvt_pk_bf16(b1[nb * 16 + quad * 4 + 2 * p],
                                      b1[nb * 16 + quad * 4 + 2 * p + 1]);
        }
    // ---- b2 per output row (row = d_loc = quad*4 + r), packed
    unsigned b2p[2][2];
    #pragma unroll
    for (int nc = 0; nc < 2; ++nc)
        #pragma unroll
        for (int p = 0; p < 2; ++p)
            b2p[nc][p] = cvt_pk_bf16(b2[nc * 16 + quad * 4 + 2 * p],
                                     b2[nc * 16 + quad * 4 + 2 * p + 1]);

    // ---------- stage A: slot s -> h fragments + gf fragment (all registers)
    auto stageA = [&](int s, bfu& h0, bfu& h1, bfu& gf) {
        const float4 a = gA[s], b = gB[s];
        const float potv = pV[s];

        float gv[8] = {a.x, a.y, a.z, a.w, b.x, b.y, b.z, b.w};
        float cube[8];
        float tp = 0.f, sp = 0.f;
        #pragma unroll
        for (int j = 0; j < 8; ++j) {
            float gc = gv[j];
            float g2 = gc * gc;
            float g3 = g2 * gc;
            tp += g2;
            sp = fmaf(g3, g3, sp);
            cube[j] = g3;
        }
        tp = quad_sum(tp);
        sp = quad_sum(sp);
        const float scale = 0.1f * __builtin_amdgcn_sqrtf(tp) *
                            __builtin_amdgcn_rcpf(__builtin_amdgcn_sqrtf(sp) + 1e-8f);

        bfu xf;
        #pragma unroll
        for (int jp = 0; jp < 4; ++jp) {
            xf.u[jp] = cvt_pk_bf16(fmaf(scale, cube[2 * jp],     gv[2 * jp]),
                                   fmaf(scale, cube[2 * jp + 1], gv[2 * jp + 1]));
            gf.u[jp] = cvt_pk_bf16(0.3f * gv[2 * jp], 0.3f * gv[2 * jp + 1]);
        }

        // GEMM1' : s^T[hid_loc][cell]; f32 bias init (unpacked from bf16 pairs); relu+pack.
        unsigned P[4][2];
        #pragma unroll
        for (int nb = 0; nb < 4; ++nb) {
            f32x4 c1;
            c1[0] = fmaf(potv, bfp_lo(w1pp[nb][0]), bfp_lo(b1p[nb][0]));
            c1[1] = fmaf(potv, bfp_hi(w1pp[nb][0]), bfp_hi(b1p[nb][0]));
            c1[2] = fmaf(potv, bfp_lo(w1pp[nb][1]), bfp_lo(b1p[nb][1]));
            c1[3] = fmaf(potv, bfp_hi(w1pp[nb][1]), bfp_hi(b1p[nb][1]));
            c1 = __builtin_amdgcn_mfma_f32_16x16x32_bf16(w1f[nb], xf.v, c1, 0, 0, 0);
            P[nb][0] = cvt_pk_bf16(fmaxf(c1[0], 0.f), fmaxf(c1[1], 0.f));
            P[nb][1] = cvt_pk_bf16(fmaxf(c1[2], 0.f), fmaxf(c1[3], 0.f));
        }

        // redistribute h with pl32 ONLY; w2f's hmap matches this layout.
        {
            unsigned x0 = P[0][0], y0 = P[1][0]; plswap(x0, y0);
            unsigned x1 = P[0][1], y1 = P[1][1]; plswap(x1, y1);
            h0.u[0] = x0; h0.u[1] = x1; h0.u[2] = y0; h0.u[3] = y1;
        }
        {
            unsigned x0 = P[2][0], y0 = P[3][0]; plswap(x0, y0);
            unsigned x1 = P[2][1], y1 = P[3][1]; plswap(x1, y1);
            h1.u[0] = x0; h1.u[1] = x1; h1.u[2] = y0; h1.u[3] = y1;
        }
    };

    // ---------- stage B: GEMM2' + permlane-coalesced store
    auto gemm2st = [&](const bfu& h0, const bfu& h1, const bfu& gf, long cb) {
        f32x4 A, B;   // nc=0 and nc=1 accumulators
        #pragma unroll
        for (int nc = 0; nc < 2; ++nc) {
            f32x4 c2;
            c2[0] = bfp_lo(b2p[nc][0]);
            c2[1] = bfp_hi(b2p[nc][0]);
            c2[2] = bfp_lo(b2p[nc][1]);
            c2[3] = bfp_hi(b2p[nc][1]);
            c2 = __builtin_amdgcn_mfma_f32_16x16x32_bf16(aid[nc],    gf.v, c2, 0, 0, 0);
            c2 = __builtin_amdgcn_mfma_f32_16x16x32_bf16(w2f[0][nc], h0.v, c2, 0, 0, 0);
            c2 = __builtin_amdgcn_mfma_f32_16x16x32_bf16(w2f[1][nc], h1.v, c2, 0, 0, 0);
            if (nc == 0) A = c2; else B = c2;
        }
        // exchange halves across lane^16 so each lane holds 8 CONTIGUOUS floats:
        // q0 -> d0-7, q1 -> d16-23, q2 -> d8-15, q3 -> d24-31
        #pragma unroll
        for (int r = 0; r < 4; ++r) {
            float ar = A[r], br = B[r];
            f2 sw = plswap16v(ar, br);
            A[r] = sw.a; B[r] = sw.b;
        }
        const int colq = ((quad & 1) << 4) | ((quad >> 1) << 3);
        float* op = out + (cb + mrow) * DIM + colq;
        *(f32x4*)op       = A;
        *(f32x4*)(op + 4) = B;
    };

    // ---------- 2-stage software pipeline over tiles, 3-deep prefetch
    bfu h0P, h1P, gfP;
    stageA(0, h0P, h1P, gfP);
    loadT(0, cell0 + (long)3 * 16);

    #pragma unroll
    for (int t = 1; t < TILES; ++t) {
        const int s = t % 3;
        bfu h0C, h1C, gfC;
        stageA(s, h0C, h1C, gfC);
        if (t + 3 < TILES) loadT(s, cell0 + (long)(t + 3) * 16);
        gemm2st(h0P, h1P, gfP, cell0 + (long)(t - 1) * 16);
        h0P = h0C; h1P = h1C; gfP = gfC;
    }
    gemm2st(h0P, h1P, gfP, cell0 + (long)(TILES - 1) * 16);
}

extern "C" void kernel_launch(void* const* d_in, const int* in_sizes, int n_in,
                              void* d_out, int out_size, void* d_ws, size_t ws_size,
                              hipStream_t stream) {
    const float* g_in = (const float*)d_in[0];
    const float* pot  = (const float*)d_in[1];
    const float* W1   = (const float*)d_in[2];
    const float* b1   = (const float*)d_in[3];
    const float* W2   = (const float*)d_in[4];
    const float* b2   = (const float*)d_in[5];
    float* out = (float*)d_out;

    const int n_cells = in_sizes[1];                     // 1048576
    const int cells_per_block = 2 * TILES * 16;          // 256
    const int blocks = (n_cells + cells_per_block - 1) / cells_per_block;

    behavior_mfma<<<blocks, 128, 0, stream>>>(g_in, pot, W1, b1, W2, b2, out);
}

// Round 8
// 245.763 us; speedup vs baseline: 1.0083x; 1.0083x over previous
//
#include <hip/hip_runtime.h>

#define DIM   32
#define HID   64

typedef __attribute__((ext_vector_type(8))) short bf16x8;   // 8 bf16 = 4 VGPRs
typedef __attribute__((ext_vector_type(4))) float f32x4;

// hardware packed f32x2 -> bf16x2 (RNE): result dword = (bf16(lo), bf16(hi))
__device__ __forceinline__ unsigned cvt_pk_bf16(float lo, float hi) {
    unsigned r;
    asm("v_cvt_pk_bf16_f32 %0, %1, %2" : "=v"(r) : "v"(lo), "v"(hi));
    return r;
}
// unpack a (lo,hi) bf16 pair back to f32
__device__ __forceinline__ float bfp_lo(unsigned u) { return __uint_as_float(u << 16); }
__device__ __forceinline__ float bfp_hi(unsigned u) { return __uint_as_float(u & 0xFFFF0000u); }

// permlane32 swap via the 2-result intrinsic (distinct result regs guaranteed).
__device__ __forceinline__ void plswap(unsigned &a, unsigned &b) {
    auto r = __builtin_amdgcn_permlane32_swap((int)a, (int)b, false, false);
    a = (unsigned)r[0];
    b = (unsigned)r[1];
}

// permlane16 swap by value: a' = [a@q0, b@q0, a@q2, b@q2], b' = [a@q1, b@q1, a@q3, b@q3]
struct f2 { float a, b; };
__device__ __forceinline__ f2 plswap16v(float a, float b) {
    auto r = __builtin_amdgcn_permlane16_swap(__float_as_int(a), __float_as_int(b),
                                              false, false);
    return { __int_as_float(r[0]), __int_as_float(r[1]) };
}

// sum over the 4 quads (lanes c, c+16, c+32, c+48) -> all lanes get the total. All-VALU.
__device__ __forceinline__ float quad_sum(float x) {
    auto r1 = __builtin_amdgcn_permlane32_swap(__float_as_int(x), __float_as_int(x),
                                               false, false);
    float t = __int_as_float(r1[0]) + __int_as_float(r1[1]);   // x[l] + x[l^32]
    auto r2 = __builtin_amdgcn_permlane16_swap(__float_as_int(t), __float_as_int(t),
                                               false, false);
    return __int_as_float(r2[0]) + __int_as_float(r2[1]);      // + 16-crossing
}

union bfu { bf16x8 v; unsigned u[4]; };

__global__ __launch_bounds__(64, 3) void behavior_mfma(
    const float* __restrict__ g_in,   // [N, 32]
    const float* __restrict__ pot,    // [N]
    const float* __restrict__ W1,     // [33, 64]
    const float* __restrict__ b1,     // [64]
    const float* __restrict__ W2,     // [64, 32]
    const float* __restrict__ b2,     // [32]
    float* __restrict__ out)          // [N, 32]
{
    const int lane = threadIdx.x & 63; // single wave per block
    const int quad = lane >> 4;        // 0..3
    const int mrow = lane & 15;        // 0..15

    const long cell0 = (long)blockIdx.x * 128;   // 8 tiles of 16 cells

    // ---------- load ring: [2 iteration slots][2 subtiles]; issued BEFORE weight setup
    float4 gA[2][2], gB[2][2]; float pV[2][2];
    auto loadPair = [&](int s, long cb) {
        #pragma unroll
        for (int u = 0; u < 2; ++u) {
            const float* gp = g_in + (cb + u * 16 + mrow) * DIM + quad * 8;
            gA[s][u] = ((const float4*)gp)[0];
            gB[s][u] = ((const float4*)gp)[1];
            pV[s][u] = pot[cb + u * 16 + mrow];
        }
    };
    loadPair(0, cell0);
    loadPair(1, cell0 + 32);

    // ---- W1 chunks as A-fragments of swapped GEMM1 (D = W1^T x^T).
    bf16x8 w1f[4];
    #pragma unroll
    for (int nb = 0; nb < 4; ++nb) {
        bfu t;
        #pragma unroll
        for (int jp = 0; jp < 4; ++jp)
            t.u[jp] = cvt_pk_bf16(W1[(quad * 8 + 2 * jp)     * HID + nb * 16 + mrow],
                                  W1[(quad * 8 + 2 * jp + 1) * HID + nb * 16 + mrow]);
        w1f[nb] = t.v;
    }
    // ---- W2 A-fragments with PERMUTED k-labeling matching pl32-only h redistribution:
    //   hmap(quad,j) = (quad>>1)*16 + (quad&1)*4 + (j>>2)*8 + (j&3)
    bf16x8 w2f[2][2];
    #pragma unroll
    for (int kc = 0; kc < 2; ++kc)
        #pragma unroll
        for (int nc = 0; nc < 2; ++nc) {
            bfu t;
            #pragma unroll
            for (int jp = 0; jp < 4; ++jp) {
                const int j0 = 2 * jp;
                const int r0 = kc * 32 + (quad >> 1) * 16 + (quad & 1) * 4
                             + ((j0 >> 2) << 3) + (j0 & 3);
                t.u[jp] = cvt_pk_bf16(W2[r0 * DIM + nc * 16 + mrow],
                                      W2[(r0 + 1) * DIM + nc * 16 + mrow]);
            }
            w2f[kc][nc] = t.v;
        }
    // ---- identity A-fragment (natural k=dim labeling) for 0.3*g pass-through
    bf16x8 aid[2];
    #pragma unroll
    for (int nc = 0; nc < 2; ++nc) {
        bfu t;
        #pragma unroll
        for (int jp = 0; jp < 4; ++jp) {
            unsigned lo = (quad * 8 + 2 * jp     == nc * 16 + mrow) ? 0x00003F80u : 0u;
            unsigned hi = (quad * 8 + 2 * jp + 1 == nc * 16 + mrow) ? 0x3F800000u : 0u;
            t.u[jp] = lo | hi;
        }
        aid[nc] = t.v;
    }
    // ---- bias path, PACKED bf16 pairs. c1[r] row = hid nb*16+quad*4+r, col = cell mrow.
    unsigned w1pp[4][2], b1p[4][2];
    #pragma unroll
    for (int nb = 0; nb < 4; ++nb)
        #pragma unroll
        for (int p = 0; p < 2; ++p) {
            w1pp[nb][p] = cvt_pk_bf16(W1[32 * HID + nb * 16 + quad * 4 + 2 * p],
                                      W1[32 * HID + nb * 16 + quad * 4 + 2 * p + 1]);
            b1p[nb][p]  = cvt_pk_bf16(b1[nb * 16 + quad * 4 + 2 * p],
                                      b1[nb * 16 + quad * 4 + 2 * p + 1]);
        }
    unsigned b2p[2][2];
    #pragma unroll
    for (int nc = 0; nc < 2; ++nc)
        #pragma unroll
        for (int p = 0; p < 2; ++p)
            b2p[nc][p] = cvt_pk_bf16(b2[nc * 16 + quad * 4 + 2 * p],
                                     b2[nc * 16 + quad * 4 + 2 * p + 1]);

    // ---------- stage A: explicit inputs -> h fragments + gf fragment (all registers)
    auto stageA = [&](float4 a, float4 b, float potv, bfu& h0, bfu& h1, bfu& gf) {
        float gv[8] = {a.x, a.y, a.z, a.w, b.x, b.y, b.z, b.w};
        float cube[8];
        float tp = 0.f, sp = 0.f;
        #pragma unroll
        for (int j = 0; j < 8; ++j) {
            float gc = gv[j];
            float g2 = gc * gc;
            float g3 = g2 * gc;
            tp += g2;
            sp = fmaf(g3, g3, sp);
            cube[j] = g3;
        }
        tp = quad_sum(tp);
        sp = quad_sum(sp);
        const float scale = 0.1f * __builtin_amdgcn_sqrtf(tp) *
                            __builtin_amdgcn_rcpf(__builtin_amdgcn_sqrtf(sp) + 1e-8f);

        bfu xf;
        #pragma unroll
        for (int jp = 0; jp < 4; ++jp) {
            xf.u[jp] = cvt_pk_bf16(fmaf(scale, cube[2 * jp],     gv[2 * jp]),
                                   fmaf(scale, cube[2 * jp + 1], gv[2 * jp + 1]));
            gf.u[jp] = cvt_pk_bf16(0.3f * gv[2 * jp], 0.3f * gv[2 * jp + 1]);
        }

        // GEMM1' : s^T[hid_loc][cell]; f32 bias init (unpacked from bf16 pairs); relu+pack.
        unsigned P[4][2];
        #pragma unroll
        for (int nb = 0; nb < 4; ++nb) {
            f32x4 c1;
            c1[0] = fmaf(potv, bfp_lo(w1pp[nb][0]), bfp_lo(b1p[nb][0]));
            c1[1] = fmaf(potv, bfp_hi(w1pp[nb][0]), bfp_hi(b1p[nb][0]));
            c1[2] = fmaf(potv, bfp_lo(w1pp[nb][1]), bfp_lo(b1p[nb][1]));
            c1[3] = fmaf(potv, bfp_hi(w1pp[nb][1]), bfp_hi(b1p[nb][1]));
            c1 = __builtin_amdgcn_mfma_f32_16x16x32_bf16(w1f[nb], xf.v, c1, 0, 0, 0);
            P[nb][0] = cvt_pk_bf16(fmaxf(c1[0], 0.f), fmaxf(c1[1], 0.f));
            P[nb][1] = cvt_pk_bf16(fmaxf(c1[2], 0.f), fmaxf(c1[3], 0.f));
        }

        // redistribute h with pl32 ONLY; w2f's hmap matches this layout.
        {
            unsigned x0 = P[0][0], y0 = P[1][0]; plswap(x0, y0);
            unsigned x1 = P[0][1], y1 = P[1][1]; plswap(x1, y1);
            h0.u[0] = x0; h0.u[1] = x1; h0.u[2] = y0; h0.u[3] = y1;
        }
        {
            unsigned x0 = P[2][0], y0 = P[3][0]; plswap(x0, y0);
            unsigned x1 = P[2][1], y1 = P[3][1]; plswap(x1, y1);
            h1.u[0] = x0; h1.u[1] = x1; h1.u[2] = y0; h1.u[3] = y1;
        }
    };

    // ---------- stage B: GEMM2' + permlane-coalesced store
    auto gemm2st = [&](const bfu& h0, const bfu& h1, const bfu& gf, long cb) {
        f32x4 A, B;   // nc=0 and nc=1 accumulators
        #pragma unroll
        for (int nc = 0; nc < 2; ++nc) {
            f32x4 c2;
            c2[0] = bfp_lo(b2p[nc][0]);
            c2[1] = bfp_hi(b2p[nc][0]);
            c2[2] = bfp_lo(b2p[nc][1]);
            c2[3] = bfp_hi(b2p[nc][1]);
            c2 = __builtin_amdgcn_mfma_f32_16x16x32_bf16(aid[nc],    gf.v, c2, 0, 0, 0);
            c2 = __builtin_amdgcn_mfma_f32_16x16x32_bf16(w2f[0][nc], h0.v, c2, 0, 0, 0);
            c2 = __builtin_amdgcn_mfma_f32_16x16x32_bf16(w2f[1][nc], h1.v, c2, 0, 0, 0);
            if (nc == 0) A = c2; else B = c2;
        }
        // exchange halves across lane^16 so each lane holds 8 CONTIGUOUS floats:
        // q0 -> d0-7, q1 -> d16-23, q2 -> d8-15, q3 -> d24-31
        #pragma unroll
        for (int r = 0; r < 4; ++r) {
            float ar = A[r], br = B[r];
            f2 sw = plswap16v(ar, br);
            A[r] = sw.a; B[r] = sw.b;
        }
        const int colq = ((quad & 1) << 4) | ((quad >> 1) << 3);
        float* op = out + (cb + mrow) * DIM + colq;
        *(f32x4*)op       = A;
        *(f32x4*)(op + 4) = B;
    };

    // ---------- main loop: 4 iterations x 2 independent subtiles, 2-iter-deep prefetch
    #pragma unroll
    for (int it = 0; it < 4; ++it) {
        const int s = it & 1;
        // snapshot both subtiles of slot s (registers; frees slot for prefetch)
        const float4 a0 = gA[s][0], b0 = gB[s][0]; const float p0 = pV[s][0];
        const float4 a1 = gA[s][1], b1x = gB[s][1]; const float p1 = pV[s][1];
        if (it + 2 < 4) loadPair(s, cell0 + (long)(it + 2) * 32);

        bfu h00, h01, g0, h10, h11, g1;
        stageA(a0, b0,  p0, h00, h01, g0);
        stageA(a1, b1x, p1, h10, h11, g1);

        const long cb = cell0 + (long)it * 32;
        gemm2st(h00, h01, g0, cb);
        gemm2st(h10, h11, g1, cb + 16);
    }
}

extern "C" void kernel_launch(void* const* d_in, const int* in_sizes, int n_in,
                              void* d_out, int out_size, void* d_ws, size_t ws_size,
                              hipStream_t stream) {
    const float* g_in = (const float*)d_in[0];
    const float* pot  = (const float*)d_in[1];
    const float* W1   = (const float*)d_in[2];
    const float* b1   = (const float*)d_in[3];
    const float* W2   = (const float*)d_in[4];
    const float* b2   = (const float*)d_in[5];
    float* out = (float*)d_out;

    const int n_cells = in_sizes[1];                     // 1048576
    const int cells_per_block = 128;                     // 1 wave x 8 tiles x 16 cells
    const int blocks = (n_cells + cells_per_block - 1) / cells_per_block;

    behavior_mfma<<<blocks, 64, 0, stream>>>(g_in, pot, W1, b1, W2, b2, out);
}

// Round 9
// 241.635 us; speedup vs baseline: 1.0256x; 1.0171x over previous
//
#include <hip/hip_runtime.h>

#define DIM   32
#define HID   64
#define SROW  36   // LDS row stride in dwords (144 B, 16B-aligned)

typedef __attribute__((ext_vector_type(8))) short bf16x8;   // 8 bf16 = 4 VGPRs
typedef __attribute__((ext_vector_type(4))) float f32x4;

// hardware packed f32x2 -> bf16x2 (RNE): result dword = (bf16(lo), bf16(hi))
__device__ __forceinline__ unsigned cvt_pk_bf16(float lo, float hi) {
    unsigned r;
    asm("v_cvt_pk_bf16_f32 %0, %1, %2" : "=v"(r) : "v"(lo), "v"(hi));
    return r;
}
// unpack a (lo,hi) bf16 pair back to f32
__device__ __forceinline__ float bfp_lo(unsigned u) { return __uint_as_float(u << 16); }
__device__ __forceinline__ float bfp_hi(unsigned u) { return __uint_as_float(u & 0xFFFF0000u); }

// permlane32 swap via the 2-result intrinsic (distinct result regs guaranteed).
__device__ __forceinline__ void plswap(unsigned &a, unsigned &b) {
    auto r = __builtin_amdgcn_permlane32_swap((int)a, (int)b, false, false);
    a = (unsigned)r[0];
    b = (unsigned)r[1];
}

// permlane16 swap by value: a' = [a@q0, b@q0, a@q2, b@q2], b' = [a@q1, b@q1, a@q3, b@q3]
struct f2 { float a, b; };
__device__ __forceinline__ f2 plswap16v(float a, float b) {
    auto r = __builtin_amdgcn_permlane16_swap(__float_as_int(a), __float_as_int(b),
                                              false, false);
    return { __int_as_float(r[0]), __int_as_float(r[1]) };
}

// sum over the 4 quads (lanes c, c+16, c+32, c+48) -> all lanes get the total. All-VALU.
__device__ __forceinline__ float quad_sum(float x) {
    auto r1 = __builtin_amdgcn_permlane32_swap(__float_as_int(x), __float_as_int(x),
                                               false, false);
    float t = __int_as_float(r1[0]) + __int_as_float(r1[1]);   // x[l] + x[l^32]
    auto r2 = __builtin_amdgcn_permlane16_swap(__float_as_int(t), __float_as_int(t),
                                               false, false);
    return __int_as_float(r2[0]) + __int_as_float(r2[1]);      // + 16-crossing
}

union bfu { bf16x8 v; unsigned u[4]; };

__global__ __launch_bounds__(64, 3) void behavior_mfma(
    const float* __restrict__ g_in,   // [N, 32]
    const float* __restrict__ pot,    // [N]
    const float* __restrict__ W1,     // [33, 64]
    const float* __restrict__ b1,     // [64]
    const float* __restrict__ W2,     // [64, 32]
    const float* __restrict__ b2,     // [32]
    float* __restrict__ out)          // [N, 32]
{
    // per-subtile store-transpose buffers (single wave -> no barriers needed)
    __shared__ __align__(16) float sT[2][16 * SROW];

    const int lane = threadIdx.x & 63; // single wave per block
    const int quad = lane >> 4;        // 0..3
    const int mrow = lane & 15;        // 0..15

    const long cell0 = (long)blockIdx.x * 128;   // 8 tiles of 16 cells

    // ---------- load ring: [2 iteration slots][2 subtiles]; issued BEFORE weight setup
    float4 gA[2][2], gB[2][2]; float pV[2][2];
    auto loadPair = [&](int s, long cb) {
        #pragma unroll
        for (int u = 0; u < 2; ++u) {
            const float* gp = g_in + (cb + u * 16 + mrow) * DIM + quad * 8;
            gA[s][u] = ((const float4*)gp)[0];
            gB[s][u] = ((const float4*)gp)[1];
            pV[s][u] = pot[cb + u * 16 + mrow];
        }
    };
    loadPair(0, cell0);
    loadPair(1, cell0 + 32);

    // ---- W1 chunks as A-fragments of swapped GEMM1 (D = W1^T x^T).
    bf16x8 w1f[4];
    #pragma unroll
    for (int nb = 0; nb < 4; ++nb) {
        bfu t;
        #pragma unroll
        for (int jp = 0; jp < 4; ++jp)
            t.u[jp] = cvt_pk_bf16(W1[(quad * 8 + 2 * jp)     * HID + nb * 16 + mrow],
                                  W1[(quad * 8 + 2 * jp + 1) * HID + nb * 16 + mrow]);
        w1f[nb] = t.v;
    }
    // ---- W2 A-fragments with PERMUTED k-labeling matching pl32-only h redistribution:
    //   hmap(quad,j) = (quad>>1)*16 + (quad&1)*4 + (j>>2)*8 + (j&3)
    bf16x8 w2f[2][2];
    #pragma unroll
    for (int kc = 0; kc < 2; ++kc)
        #pragma unroll
        for (int nc = 0; nc < 2; ++nc) {
            bfu t;
            #pragma unroll
            for (int jp = 0; jp < 4; ++jp) {
                const int j0 = 2 * jp;
                const int r0 = kc * 32 + (quad >> 1) * 16 + (quad & 1) * 4
                             + ((j0 >> 2) << 3) + (j0 & 3);
                t.u[jp] = cvt_pk_bf16(W2[r0 * DIM + nc * 16 + mrow],
                                      W2[(r0 + 1) * DIM + nc * 16 + mrow]);
            }
            w2f[kc][nc] = t.v;
        }
    // ---- identity A-fragment (natural k=dim labeling) for 0.3*g pass-through
    bf16x8 aid[2];
    #pragma unroll
    for (int nc = 0; nc < 2; ++nc) {
        bfu t;
        #pragma unroll
        for (int jp = 0; jp < 4; ++jp) {
            unsigned lo = (quad * 8 + 2 * jp     == nc * 16 + mrow) ? 0x00003F80u : 0u;
            unsigned hi = (quad * 8 + 2 * jp + 1 == nc * 16 + mrow) ? 0x3F800000u : 0u;
            t.u[jp] = lo | hi;
        }
        aid[nc] = t.v;
    }
    // ---- bias path, PACKED bf16 pairs. c1[r] row = hid nb*16+quad*4+r, col = cell mrow.
    unsigned w1pp[4][2], b1p[4][2];
    #pragma unroll
    for (int nb = 0; nb < 4; ++nb)
        #pragma unroll
        for (int p = 0; p < 2; ++p) {
            w1pp[nb][p] = cvt_pk_bf16(W1[32 * HID + nb * 16 + quad * 4 + 2 * p],
                                      W1[32 * HID + nb * 16 + quad * 4 + 2 * p + 1]);
            b1p[nb][p]  = cvt_pk_bf16(b1[nb * 16 + quad * 4 + 2 * p],
                                      b1[nb * 16 + quad * 4 + 2 * p + 1]);
        }
    unsigned b2p[2][2];
    #pragma unroll
    for (int nc = 0; nc < 2; ++nc)
        #pragma unroll
        for (int p = 0; p < 2; ++p)
            b2p[nc][p] = cvt_pk_bf16(b2[nc * 16 + quad * 4 + 2 * p],
                                     b2[nc * 16 + quad * 4 + 2 * p + 1]);

    // ---------- stage A: explicit inputs -> h fragments + gf fragment (all registers)
    auto stageA = [&](float4 a, float4 b, float potv, bfu& h0, bfu& h1, bfu& gf) {
        float gv[8] = {a.x, a.y, a.z, a.w, b.x, b.y, b.z, b.w};
        float cube[8];
        float tp = 0.f, sp = 0.f;
        #pragma unroll
        for (int j = 0; j < 8; ++j) {
            float gc = gv[j];
            float g2 = gc * gc;
            float g3 = g2 * gc;
            tp += g2;
            sp = fmaf(g3, g3, sp);
            cube[j] = g3;
        }
        tp = quad_sum(tp);
        sp = quad_sum(sp);
        const float scale = 0.1f * __builtin_amdgcn_sqrtf(tp) *
                            __builtin_amdgcn_rcpf(__builtin_amdgcn_sqrtf(sp) + 1e-8f);

        bfu xf;
        #pragma unroll
        for (int jp = 0; jp < 4; ++jp) {
            xf.u[jp] = cvt_pk_bf16(fmaf(scale, cube[2 * jp],     gv[2 * jp]),
                                   fmaf(scale, cube[2 * jp + 1], gv[2 * jp + 1]));
            gf.u[jp] = cvt_pk_bf16(0.3f * gv[2 * jp], 0.3f * gv[2 * jp + 1]);
        }

        // GEMM1' : s^T[hid_loc][cell]; f32 bias init (unpacked from bf16 pairs); relu+pack.
        unsigned P[4][2];
        #pragma unroll
        for (int nb = 0; nb < 4; ++nb) {
            f32x4 c1;
            c1[0] = fmaf(potv, bfp_lo(w1pp[nb][0]), bfp_lo(b1p[nb][0]));
            c1[1] = fmaf(potv, bfp_hi(w1pp[nb][0]), bfp_hi(b1p[nb][0]));
            c1[2] = fmaf(potv, bfp_lo(w1pp[nb][1]), bfp_lo(b1p[nb][1]));
            c1[3] = fmaf(potv, bfp_hi(w1pp[nb][1]), bfp_hi(b1p[nb][1]));
            c1 = __builtin_amdgcn_mfma_f32_16x16x32_bf16(w1f[nb], xf.v, c1, 0, 0, 0);
            P[nb][0] = cvt_pk_bf16(fmaxf(c1[0], 0.f), fmaxf(c1[1], 0.f));
            P[nb][1] = cvt_pk_bf16(fmaxf(c1[2], 0.f), fmaxf(c1[3], 0.f));
        }

        // redistribute h with pl32 ONLY; w2f's hmap matches this layout.
        {
            unsigned x0 = P[0][0], y0 = P[1][0]; plswap(x0, y0);
            unsigned x1 = P[0][1], y1 = P[1][1]; plswap(x1, y1);
            h0.u[0] = x0; h0.u[1] = x1; h0.u[2] = y0; h0.u[3] = y1;
        }
        {
            unsigned x0 = P[2][0], y0 = P[3][0]; plswap(x0, y0);
            unsigned x1 = P[2][1], y1 = P[3][1]; plswap(x1, y1);
            h1.u[0] = x0; h1.u[1] = x1; h1.u[2] = y0; h1.u[3] = y1;
        }
    };

    // ---------- stage B: GEMM2' + LDS lane-transpose + fully-DENSE stores
    auto gemm2st = [&](const bfu& h0, const bfu& h1, const bfu& gf, long cb, int u) {
        f32x4 A, B;   // nc=0 and nc=1 accumulators
        #pragma unroll
        for (int nc = 0; nc < 2; ++nc) {
            f32x4 c2;
            c2[0] = bfp_lo(b2p[nc][0]);
            c2[1] = bfp_hi(b2p[nc][0]);
            c2[2] = bfp_lo(b2p[nc][1]);
            c2[3] = bfp_hi(b2p[nc][1]);
            c2 = __builtin_amdgcn_mfma_f32_16x16x32_bf16(aid[nc],    gf.v, c2, 0, 0, 0);
            c2 = __builtin_amdgcn_mfma_f32_16x16x32_bf16(w2f[0][nc], h0.v, c2, 0, 0, 0);
            c2 = __builtin_amdgcn_mfma_f32_16x16x32_bf16(w2f[1][nc], h1.v, c2, 0, 0, 0);
            if (nc == 0) A = c2; else B = c2;
        }
        // exchange across lane^16: lane(q,m) then holds cell m, dims [colq, colq+8)
        #pragma unroll
        for (int r = 0; r < 4; ++r) {
            float ar = A[r], br = B[r];
            f2 sw = plswap16v(ar, br);
            A[r] = sw.a; B[r] = sw.b;
        }
        const int colq = ((quad & 1) << 4) | ((quad >> 1) << 3);

        // LDS transpose: write [cell=m][dim colq..colq+8), read dense, store dense
        float* buf = sT[u];
        *(f32x4*)&buf[mrow * SROW + colq]     = A;
        *(f32x4*)&buf[mrow * SROW + colq + 4] = B;
        const int rc = lane >> 3;            // 0..7
        const int kc = (lane & 7) * 4;       // dim group
        f32x4 d0 = *(const f32x4*)&buf[rc * SROW + kc];
        f32x4 d1 = *(const f32x4*)&buf[(8 + rc) * SROW + kc];
        // dense: instruction 1 covers bytes [cb*128, +1024), lane l -> +l*16
        float* gout = out + cb * DIM;
        *(f32x4*)(gout + lane * 4)       = d0;
        *(f32x4*)(gout + 256 + lane * 4) = d1;
    };

    // ---------- main loop: 4 iterations x 2 independent subtiles, 2-iter-deep prefetch
    #pragma unroll
    for (int it = 0; it < 4; ++it) {
        const int s = it & 1;
        // snapshot both subtiles of slot s (registers; frees slot for prefetch)
        const float4 a0 = gA[s][0], b0 = gB[s][0]; const float p0 = pV[s][0];
        const float4 a1 = gA[s][1], b1x = gB[s][1]; const float p1 = pV[s][1];
        if (it + 2 < 4) loadPair(s, cell0 + (long)(it + 2) * 32);

        bfu h00, h01, g0, h10, h11, g1;
        stageA(a0, b0,  p0, h00, h01, g0);
        stageA(a1, b1x, p1, h10, h11, g1);

        const long cb = cell0 + (long)it * 32;
        gemm2st(h00, h01, g0, cb, 0);
        gemm2st(h10, h11, g1, cb + 16, 1);
    }
}

extern "C" void kernel_launch(void* const* d_in, const int* in_sizes, int n_in,
                              void* d_out, int out_size, void* d_ws, size_t ws_size,
                              hipStream_t stream) {
    const float* g_in = (const float*)d_in[0];
    const float* pot  = (const float*)d_in[1];
    const float* W1   = (const float*)d_in[2];
    const float* b1   = (const float*)d_in[3];
    const float* W2   = (const float*)d_in[4];
    const float* b2   = (const float*)d_in[5];
    float* out = (float*)d_out;

    const int n_cells = in_sizes[1];                     // 1048576
    const int cells_per_block = 128;                     // 1 wave x 8 tiles x 16 cells
    const int blocks = (n_cells + cells_per_block - 1) / cells_per_block;

    behavior_mfma<<<blocks, 64, 0, stream>>>(g_in, pot, W1, b1, W2, b2, out);
}